// Round 10
// baseline (130.442 us; speedup 1.0000x reference)
//
#include <hip/hip_runtime.h>

namespace {

typedef __attribute__((ext_vector_type(4))) float f32x4;
typedef __attribute__((ext_vector_type(8))) short bf16x8;

constexpr int WFRAG_ELEMS = 24 * 8 * 64 * 8;          // 98304 bf16
constexpr int WFRAG_BYTES = WFRAG_ELEMS * 2;          // 196608
constexpr int BIAS_ELEMS  = 8 * 64 * 64;              // 32768 f32
constexpr size_t WS_NEEDED = (size_t)WFRAG_BYTES + (size_t)BIAS_ELEMS * 4;  // 327680

// LDS layout (bytes), all overlaid in one 48KB arena:
//  - XS [0..32768): x staged as MFMA A-fragments (dead after proj MFMAs)
//  - CB [0..49152): C = proj+bias, bf16, XOR-swizzled (written after XS dies;
//                   dead after score-phase fragment loads)
//  - PB [wave*4096 .. +4096): per-wave f32 store-bounce tiles (used only
//                   after the frags-loaded barrier, when CB is dead)
constexpr int XS_OFF    = 0;
constexpr int CB_OFF    = 0;
constexpr int PB_STRIDE = 4096;
constexpr int LDS_TOTAL = 49152;           // -> 3 blocks/CU

__device__ __forceinline__ unsigned short f2bf(float f) {
  unsigned u = __float_as_uint(f);
  u += 0x7fffu + ((u >> 16) & 1u);   // RNE
  return (unsigned short)(u >> 16);
}

// byte offset of C[row][col] (bf16) with 16B-slot XOR swizzle
__device__ __forceinline__ int cb_addr(int row, int col) {
  const int slot = (col >> 3) ^ (row & 7);
  return CB_OFF + row * 768 + (slot << 4) + ((col & 7) << 1);
}

// bounce-tile slot: P[row16][kt], 16B slot = (ktq ^ row16) & 15
__device__ __forceinline__ int pb_addr(int wavebase, int row16, int ktq) {
  return wavebase + row16 * 256 + (((ktq ^ row16) & 15) << 4);
}

__global__ void prep(const float* __restrict__ w_in,
                     const float* __restrict__ btab,
                     const int*   __restrict__ rpidx,
                     unsigned short* __restrict__ wfrag,
                     float* __restrict__ biasx) {
  const int t = blockIdx.x * 256 + threadIdx.x;
  if (t < WFRAG_ELEMS) {
    const int j    = t & 7;
    const int lane = (t >> 3) & 63;
    const int kk   = (t >> 9) & 7;
    const int nt   = t >> 12;
    const int k    = kk * 32 + (lane >> 4) * 8 + j;
    const int col  = nt * 16 + (lane & 15);
    wfrag[t] = f2bf(w_in[k * 384 + col]);
  } else if (t < WFRAG_ELEMS + BIAS_ELEMS) {
    const int o = t - WFRAG_ELEMS;
    const int j = o & 63, i = (o >> 6) & 63, h = o >> 12;
    biasx[o] = __expf(btab[rpidx[i * 64 + j] * 8 + h]);   // pre-exponentiated
  }
}

template <bool USE_WS>
__global__ __launch_bounds__(256, 3)
void fused_mhaw(const float* __restrict__ x,
                const int*   __restrict__ reidx,
                const float* __restrict__ w_in,
                const float* __restrict__ b_in,
                const float* __restrict__ btab,
                const int*   __restrict__ rpidx,
                const unsigned short* __restrict__ wfrag,
                const float* __restrict__ biasx,
                float*       __restrict__ out) {
  extern __shared__ char lds[];
  unsigned short* xs = reinterpret_cast<unsigned short*>(lds + XS_OFF);

  const int tid  = threadIdx.x;
  const int b    = blockIdx.x >> 10;
  const int win  = blockIdx.x & 1023;
  const int wh   = win >> 5, ww = win & 31;
  const int wave = tid >> 6, lane = tid & 63;
  const int l15  = lane & 15, q = lane >> 4;
  const int pbase = wave * PB_STRIDE;

  // ---------------- stage gathered x rows as MFMA A-fragments --------------
  {
    const int srow = tid >> 2;       // token row this thread stages
    const int part = tid & 3;        // 32-float chunk within each K-half
    const int sm_t = srow >> 4, sr15 = srow & 15;
    const int swr  = sr15 ^ (part << 1);   // break 8-way write conflict
    const int tokv = reidx[(wh * 8 + (srow >> 3)) * 256 + ww * 8 + (srow & 7)];
    const float* xrow = x + ((size_t)b * 65536 + (size_t)tokv) * 256;
#pragma unroll
    for (int hf = 0; hf < 2; ++hf) {
      const float* src = xrow + hf * 128 + part * 32;
#pragma unroll
      for (int g = 0; g < 4; ++g) {
        const float4 v0 = *reinterpret_cast<const float4*>(src + g * 8);
        const float4 v1 = *reinterpret_cast<const float4*>(src + g * 8 + 4);
        bf16x8 u;
        u[0] = (short)f2bf(v0.x); u[1] = (short)f2bf(v0.y);
        u[2] = (short)f2bf(v0.z); u[3] = (short)f2bf(v0.w);
        u[4] = (short)f2bf(v1.x); u[5] = (short)f2bf(v1.y);
        u[6] = (short)f2bf(v1.z); u[7] = (short)f2bf(v1.w);
        *reinterpret_cast<bf16x8*>(
            xs + ((sm_t * 8 + hf * 4 + part) * 64 + g * 16 + swr) * 8) = u;
      }
    }
  }
  __syncthreads();

  // ------- projection (transposed): accT[n][m] = (W_tile)^T (X_tile)^T -----
  f32x4 acc[6][4];
#pragma unroll
  for (int n = 0; n < 6; ++n)
#pragma unroll
    for (int m = 0; m < 4; ++m) acc[n][m] = (f32x4){0.f, 0.f, 0.f, 0.f};

#pragma unroll
  for (int kk = 0; kk < 8; ++kk) {
    const int rlane = q * 16 + (l15 ^ ((kk & 3) << 1));   // un-swizzle
    bf16x8 af[4];
#pragma unroll
    for (int m = 0; m < 4; ++m)
      af[m] = *reinterpret_cast<const bf16x8*>(xs + ((m * 8 + kk) * 64 + rlane) * 8);
#pragma unroll
    for (int n = 0; n < 6; ++n) {
      bf16x8 bfr;
      if (USE_WS) {
        bfr = *reinterpret_cast<const bf16x8*>(
            wfrag + (((wave * 6 + n) * 8 + kk) * 64 + lane) * 8);
      } else {
        const int colg = wave * 96 + n * 16 + l15;
#pragma unroll
        for (int jj = 0; jj < 8; ++jj)
          bfr[jj] = (short)f2bf(w_in[(kk * 32 + q * 8 + jj) * 384 + colg]);
      }
#pragma unroll
      for (int m = 0; m < 4; ++m)
        acc[n][m] = __builtin_amdgcn_mfma_f32_16x16x32_bf16(bfr, af[m], acc[n][m], 0, 0, 0);
    }
  }
  __syncthreads();   // xs dead; CB overlays it

  // write C (+bias) to swizzled LDS buffer as bf16 — vectorized ds_write_b64
#pragma unroll
  for (int n = 0; n < 6; ++n) {
    const int colb = wave * 96 + n * 16 + q * 4;
    const float4 bv = *reinterpret_cast<const float4*>(b_in + colb);
#pragma unroll
    for (int m = 0; m < 4; ++m) {
      ushort4 u;
      u.x = f2bf(acc[n][m][0] + bv.x);
      u.y = f2bf(acc[n][m][1] + bv.y);
      u.z = f2bf(acc[n][m][2] + bv.z);
      u.w = f2bf(acc[n][m][3] + bv.w);
      *reinterpret_cast<ushort4*>(lds + cb_addr(m * 16 + l15, colb)) = u;
    }
  }
  __syncthreads();

  // ---------------- per-head K·Qᵀ (=Sᵀ) + bias + softmax -------------------
  const bf16x8 vz = {0, 0, 0, 0, 0, 0, 0, 0};
  const f32x4 cz = {0.f, 0.f, 0.f, 0.f};
  const int h0 = wave * 2, h1 = h0 + 1;

  // No max-subtraction: w_in pre-scaling bounds |s| <~ 8, exp is safe in f32
  // and the normalized ratio is mathematically unchanged.
  auto softmax_store = [&](int h, f32x4 (&s)[4][4]) {
    const size_t obase = (((size_t)h * 2 + b) * 1024 + win) * 4096;
#pragma unroll
    for (int bi = 0; bi < 4; ++bi) {
      const int qt = bi * 16 + l15;           // query row this lane owns
      f32x4 p[4];
      float sum = 0.f;
#pragma unroll
      for (int ai = 0; ai < 4; ++ai) {
        if (USE_WS) {
          const f32x4 eb = *reinterpret_cast<const f32x4*>(
              biasx + ((size_t)(h * 64 + qt)) * 64 + ai * 16 + q * 4);
#pragma unroll
          for (int r = 0; r < 4; ++r)
            p[ai][r] = __expf(s[ai][bi][r]) * eb[r];
        } else {
#pragma unroll
          for (int r = 0; r < 4; ++r)
            p[ai][r] = __expf(s[ai][bi][r] +
                              btab[rpidx[qt * 64 + ai * 16 + q * 4 + r] * 8 + h]);
        }
#pragma unroll
        for (int r = 0; r < 4; ++r) sum += p[ai][r];
      }
      sum += __shfl_xor(sum, 16);
      sum += __shfl_xor(sum, 32);
      const float inv = __builtin_amdgcn_rcpf(sum);

      // store via per-wave LDS bounce: 1KB contiguous per instruction
#pragma unroll
      for (int ai = 0; ai < 4; ++ai) {
        const f32x4 o = p[ai] * inv;
        *reinterpret_cast<f32x4*>(lds + pb_addr(pbase, l15, ai * 4 + q)) = o;
      }
#pragma unroll
      for (int i = 0; i < 4; ++i) {
        const int row16 = i * 4 + q;
        const f32x4 v = *reinterpret_cast<const f32x4*>(
            lds + pb_addr(pbase, row16, l15));
        *reinterpret_cast<f32x4*>(
            out + obase + (size_t)(bi * 16 + row16) * 64 + l15 * 4) = v;
      }
    }
  };

  // h0 fragments -> scores (frees frag regs before h1 loads)
  f32x4 s0t[4][4];
  {
    bf16x8 aq[4], bk[4];
#pragma unroll
    for (int mi = 0; mi < 4; ++mi)
      aq[mi] = (lane < 48)
                   ? *reinterpret_cast<const bf16x8*>(lds + cb_addr(mi * 16 + l15, h0 * 24 + q * 8))
                   : vz;
#pragma unroll
    for (int ni = 0; ni < 4; ++ni)
      bk[ni] = (lane < 48)
                   ? *reinterpret_cast<const bf16x8*>(lds + cb_addr(ni * 16 + l15, 192 + h0 * 24 + q * 8))
                   : vz;
#pragma unroll
    for (int ai = 0; ai < 4; ++ai)
#pragma unroll
      for (int bi = 0; bi < 4; ++bi)
        s0t[ai][bi] = __builtin_amdgcn_mfma_f32_16x16x32_bf16(bk[ai], aq[bi], cz, 0, 0, 0);
  }

  // h1 fragments (kept in regs across h0's softmax)
  bf16x8 aq1[4], bk1[4];
#pragma unroll
  for (int mi = 0; mi < 4; ++mi)
    aq1[mi] = (lane < 48)
                  ? *reinterpret_cast<const bf16x8*>(lds + cb_addr(mi * 16 + l15, h1 * 24 + q * 8))
                  : vz;
#pragma unroll
  for (int ni = 0; ni < 4; ++ni)
    bk1[ni] = (lane < 48)
                  ? *reinterpret_cast<const bf16x8*>(lds + cb_addr(ni * 16 + l15, 192 + h1 * 24 + q * 8))
                  : vz;

  __syncthreads();   // all CB reads done block-wide; PB may overwrite CB

  softmax_store(h0, s0t);

  f32x4 s1t[4][4];
#pragma unroll
  for (int ai = 0; ai < 4; ++ai)
#pragma unroll
    for (int bi = 0; bi < 4; ++bi)
      s1t[ai][bi] = __builtin_amdgcn_mfma_f32_16x16x32_bf16(bk1[ai], aq1[bi], cz, 0, 0, 0);

  softmax_store(h1, s1t);
}

}  // namespace

extern "C" void kernel_launch(void* const* d_in, const int* in_sizes, int n_in,
                              void* d_out, int out_size, void* d_ws, size_t ws_size,
                              hipStream_t stream) {
  const float* x     = (const float*)d_in[0];
  const int*   reidx = (const int*)d_in[1];
  const float* w_in  = (const float*)d_in[2];
  const float* b_in  = (const float*)d_in[3];
  const float* btab  = (const float*)d_in[4];
  const int*   rpidx = (const int*)d_in[5];
  float* out = (float*)d_out;

  const bool use_ws = ws_size >= WS_NEEDED;
  unsigned short* wfrag = (unsigned short*)d_ws;
  float* biasx = (float*)((char*)d_ws + WFRAG_BYTES);

  if (use_ws) {
    prep<<<dim3((WFRAG_ELEMS + BIAS_ELEMS + 255) / 256), dim3(256), 0, stream>>>(
        w_in, btab, rpidx, wfrag, biasx);
    fused_mhaw<true><<<dim3(2048), dim3(256), LDS_TOTAL, stream>>>(
        x, reidx, w_in, b_in, btab, rpidx, wfrag, biasx, out);
  } else {
    fused_mhaw<false><<<dim3(2048), dim3(256), LDS_TOTAL, stream>>>(
        x, reidx, w_in, b_in, btab, rpidx, nullptr, nullptr, out);
  }
}

// Round 11
// 111.649 us; speedup vs baseline: 1.1683x; 1.1683x over previous
//
#include <hip/hip_runtime.h>

namespace {

typedef __attribute__((ext_vector_type(4))) float f32x4;
typedef __attribute__((ext_vector_type(8))) short bf16x8;

constexpr int WFRAG_ELEMS = 24 * 8 * 64 * 8;          // 98304 bf16
constexpr int WFRAG_BYTES = WFRAG_ELEMS * 2;          // 196608
constexpr int BIAS_ELEMS  = 8 * 64 * 64;              // 32768 f32
constexpr size_t WS_NEEDED = (size_t)WFRAG_BYTES + (size_t)BIAS_ELEMS * 4;  // 327680

// LDS layout (bytes), all overlaid in one 48KB arena:
//  - XS [0..32768): x staged as MFMA A-fragments (dead after proj MFMAs)
//  - CB [0..49152): C = proj+bias, bf16, XOR-swizzled (written after XS dies;
//                   dead after score-phase fragment loads)
//  - PB [wave*4096 .. +4096): per-wave f32 store-bounce tiles (used only
//                   after the frags-loaded barrier, when CB is dead)
constexpr int XS_OFF    = 0;
constexpr int CB_OFF    = 0;
constexpr int PB_STRIDE = 4096;
constexpr int LDS_TOTAL = 49152;           // -> 3 blocks/CU

__device__ __forceinline__ unsigned short f2bf(float f) {
  unsigned u = __float_as_uint(f);
  u += 0x7fffu + ((u >> 16) & 1u);   // RNE
  return (unsigned short)(u >> 16);
}

// byte offset of C[row][col] (bf16) with 16B-slot XOR swizzle
__device__ __forceinline__ int cb_addr(int row, int col) {
  const int slot = (col >> 3) ^ (row & 7);
  return CB_OFF + row * 768 + (slot << 4) + ((col & 7) << 1);
}

// bounce-tile slot: P[row16][kt], 16B slot = (ktq ^ row16) & 15
__device__ __forceinline__ int pb_addr(int wavebase, int row16, int ktq) {
  return wavebase + row16 * 256 + (((ktq ^ row16) & 15) << 4);
}

__global__ void prep(const float* __restrict__ w_in,
                     const float* __restrict__ btab,
                     const int*   __restrict__ rpidx,
                     unsigned short* __restrict__ wfrag,
                     float* __restrict__ biasx) {
  const int t = blockIdx.x * 256 + threadIdx.x;
  if (t < WFRAG_ELEMS) {
    const int j    = t & 7;
    const int lane = (t >> 3) & 63;
    const int kk   = (t >> 9) & 7;
    const int nt   = t >> 12;
    const int k    = kk * 32 + (lane >> 4) * 8 + j;
    const int col  = nt * 16 + (lane & 15);
    wfrag[t] = f2bf(w_in[k * 384 + col]);
  } else if (t < WFRAG_ELEMS + BIAS_ELEMS) {
    const int o = t - WFRAG_ELEMS;
    const int j = o & 63, i = (o >> 6) & 63, h = o >> 12;
    biasx[o] = __expf(btab[rpidx[i * 64 + j] * 8 + h]);   // pre-exponentiated
  }
}

template <bool USE_WS>
__global__ __launch_bounds__(256, 3)
void fused_mhaw(const float* __restrict__ x,
                const int*   __restrict__ reidx,
                const float* __restrict__ w_in,
                const float* __restrict__ b_in,
                const float* __restrict__ btab,
                const int*   __restrict__ rpidx,
                const unsigned short* __restrict__ wfrag,
                const float* __restrict__ biasx,
                float*       __restrict__ out) {
  extern __shared__ char lds[];
  unsigned short* xs = reinterpret_cast<unsigned short*>(lds + XS_OFF);

  const int tid  = threadIdx.x;
  const int b    = blockIdx.x >> 10;
  const int win  = blockIdx.x & 1023;
  const int wh   = win >> 5, ww = win & 31;
  const int wave = tid >> 6, lane = tid & 63;
  const int l15  = lane & 15, q = lane >> 4;
  const int pbase = wave * PB_STRIDE;

  // ---------------- stage gathered x rows as MFMA A-fragments --------------
  {
    const int srow = tid >> 2;       // token row this thread stages
    const int part = tid & 3;        // 32-float chunk within each K-half
    const int sm_t = srow >> 4, sr15 = srow & 15;
    const int swr  = sr15 ^ (part << 1);   // break 8-way write conflict
    const int tokv = reidx[(wh * 8 + (srow >> 3)) * 256 + ww * 8 + (srow & 7)];
    const float* xrow = x + ((size_t)b * 65536 + (size_t)tokv) * 256;
#pragma unroll
    for (int hf = 0; hf < 2; ++hf) {
      const float* src = xrow + hf * 128 + part * 32;
#pragma unroll
      for (int g = 0; g < 4; ++g) {
        const float4 v0 = *reinterpret_cast<const float4*>(src + g * 8);
        const float4 v1 = *reinterpret_cast<const float4*>(src + g * 8 + 4);
        bf16x8 u;
        u[0] = (short)f2bf(v0.x); u[1] = (short)f2bf(v0.y);
        u[2] = (short)f2bf(v0.z); u[3] = (short)f2bf(v0.w);
        u[4] = (short)f2bf(v1.x); u[5] = (short)f2bf(v1.y);
        u[6] = (short)f2bf(v1.z); u[7] = (short)f2bf(v1.w);
        *reinterpret_cast<bf16x8*>(
            xs + ((sm_t * 8 + hf * 4 + part) * 64 + g * 16 + swr) * 8) = u;
      }
    }
  }
  __syncthreads();

  // ------- projection (transposed): accT[n][m] = (W_tile)^T (X_tile)^T -----
  f32x4 acc[6][4];
#pragma unroll
  for (int n = 0; n < 6; ++n)
#pragma unroll
    for (int m = 0; m < 4; ++m) acc[n][m] = (f32x4){0.f, 0.f, 0.f, 0.f};

#pragma unroll
  for (int kk = 0; kk < 8; ++kk) {
    const int rlane = q * 16 + (l15 ^ ((kk & 3) << 1));   // un-swizzle
    bf16x8 af[4];
#pragma unroll
    for (int m = 0; m < 4; ++m)
      af[m] = *reinterpret_cast<const bf16x8*>(xs + ((m * 8 + kk) * 64 + rlane) * 8);
#pragma unroll
    for (int n = 0; n < 6; ++n) {
      bf16x8 bfr;
      if (USE_WS) {
        bfr = *reinterpret_cast<const bf16x8*>(
            wfrag + (((wave * 6 + n) * 8 + kk) * 64 + lane) * 8);
      } else {
        const int colg = wave * 96 + n * 16 + l15;
#pragma unroll
        for (int jj = 0; jj < 8; ++jj)
          bfr[jj] = (short)f2bf(w_in[(kk * 32 + q * 8 + jj) * 384 + colg]);
      }
#pragma unroll
      for (int m = 0; m < 4; ++m)
        acc[n][m] = __builtin_amdgcn_mfma_f32_16x16x32_bf16(bfr, af[m], acc[n][m], 0, 0, 0);
    }
  }
  __syncthreads();   // xs dead; CB overlays it

  // write C (+bias) to swizzled LDS buffer as bf16 — vectorized ds_write_b64
#pragma unroll
  for (int n = 0; n < 6; ++n) {
    const int colb = wave * 96 + n * 16 + q * 4;
    const float4 bv = *reinterpret_cast<const float4*>(b_in + colb);
#pragma unroll
    for (int m = 0; m < 4; ++m) {
      ushort4 u;
      u.x = f2bf(acc[n][m][0] + bv.x);
      u.y = f2bf(acc[n][m][1] + bv.y);
      u.z = f2bf(acc[n][m][2] + bv.z);
      u.w = f2bf(acc[n][m][3] + bv.w);
      *reinterpret_cast<ushort4*>(lds + cb_addr(m * 16 + l15, colb)) = u;
    }
  }
  __syncthreads();

  // ---------------- per-head K·Qᵀ (=Sᵀ) + bias + softmax -------------------
  const bf16x8 vz = {0, 0, 0, 0, 0, 0, 0, 0};
  const f32x4 cz = {0.f, 0.f, 0.f, 0.f};
  const int h0 = wave * 2, h1 = h0 + 1;

  // No max-subtraction: w_in pre-scaling bounds |s| <~ 8, exp is safe in f32
  // and the normalized ratio is mathematically unchanged.
  auto softmax_store = [&](int h, f32x4 (&s)[4][4]) {
    const size_t obase = (((size_t)h * 2 + b) * 1024 + win) * 4096;
#pragma unroll
    for (int bi = 0; bi < 4; ++bi) {
      const int qt = bi * 16 + l15;           // query row this lane owns
      f32x4 p[4];
      float sum = 0.f;
#pragma unroll
      for (int ai = 0; ai < 4; ++ai) {
        if (USE_WS) {
          const f32x4 eb = *reinterpret_cast<const f32x4*>(
              biasx + ((size_t)(h * 64 + qt)) * 64 + ai * 16 + q * 4);
#pragma unroll
          for (int r = 0; r < 4; ++r)
            p[ai][r] = __expf(s[ai][bi][r]) * eb[r];
        } else {
#pragma unroll
          for (int r = 0; r < 4; ++r)
            p[ai][r] = __expf(s[ai][bi][r] +
                              btab[rpidx[qt * 64 + ai * 16 + q * 4 + r] * 8 + h]);
        }
#pragma unroll
        for (int r = 0; r < 4; ++r) sum += p[ai][r];
      }
      sum += __shfl_xor(sum, 16);
      sum += __shfl_xor(sum, 32);
      const float inv = __builtin_amdgcn_rcpf(sum);

      // store via per-wave LDS bounce: 1KB contiguous per instruction
#pragma unroll
      for (int ai = 0; ai < 4; ++ai) {
        const f32x4 o = p[ai] * inv;
        *reinterpret_cast<f32x4*>(lds + pb_addr(pbase, l15, ai * 4 + q)) = o;
      }
#pragma unroll
      for (int i = 0; i < 4; ++i) {
        const int row16 = i * 4 + q;
        const f32x4 v = *reinterpret_cast<const f32x4*>(
            lds + pb_addr(pbase, row16, l15));
        __builtin_nontemporal_store(
            v, reinterpret_cast<f32x4*>(
                   out + obase + (size_t)(bi * 16 + row16) * 64 + l15 * 4));
      }
    }
  };

  // h0 fragments -> scores (frees frag regs before h1 loads)
  f32x4 s0t[4][4];
  {
    bf16x8 aq[4], bk[4];
#pragma unroll
    for (int mi = 0; mi < 4; ++mi)
      aq[mi] = (lane < 48)
                   ? *reinterpret_cast<const bf16x8*>(lds + cb_addr(mi * 16 + l15, h0 * 24 + q * 8))
                   : vz;
#pragma unroll
    for (int ni = 0; ni < 4; ++ni)
      bk[ni] = (lane < 48)
                   ? *reinterpret_cast<const bf16x8*>(lds + cb_addr(ni * 16 + l15, 192 + h0 * 24 + q * 8))
                   : vz;
#pragma unroll
    for (int ai = 0; ai < 4; ++ai)
#pragma unroll
      for (int bi = 0; bi < 4; ++bi)
        s0t[ai][bi] = __builtin_amdgcn_mfma_f32_16x16x32_bf16(bk[ai], aq[bi], cz, 0, 0, 0);
  }

  // h1 fragments (kept in regs across h0's softmax)
  bf16x8 aq1[4], bk1[4];
#pragma unroll
  for (int mi = 0; mi < 4; ++mi)
    aq1[mi] = (lane < 48)
                  ? *reinterpret_cast<const bf16x8*>(lds + cb_addr(mi * 16 + l15, h1 * 24 + q * 8))
                  : vz;
#pragma unroll
  for (int ni = 0; ni < 4; ++ni)
    bk1[ni] = (lane < 48)
                  ? *reinterpret_cast<const bf16x8*>(lds + cb_addr(ni * 16 + l15, 192 + h1 * 24 + q * 8))
                  : vz;

  __syncthreads();   // all CB reads done block-wide; PB may overwrite CB

  softmax_store(h0, s0t);

  f32x4 s1t[4][4];
#pragma unroll
  for (int ai = 0; ai < 4; ++ai)
#pragma unroll
    for (int bi = 0; bi < 4; ++bi)
      s1t[ai][bi] = __builtin_amdgcn_mfma_f32_16x16x32_bf16(bk1[ai], aq1[bi], cz, 0, 0, 0);

  softmax_store(h1, s1t);
}

}  // namespace

extern "C" void kernel_launch(void* const* d_in, const int* in_sizes, int n_in,
                              void* d_out, int out_size, void* d_ws, size_t ws_size,
                              hipStream_t stream) {
  const float* x     = (const float*)d_in[0];
  const int*   reidx = (const int*)d_in[1];
  const float* w_in  = (const float*)d_in[2];
  const float* b_in  = (const float*)d_in[3];
  const float* btab  = (const float*)d_in[4];
  const int*   rpidx = (const int*)d_in[5];
  float* out = (float*)d_out;

  const bool use_ws = ws_size >= WS_NEEDED;
  unsigned short* wfrag = (unsigned short*)d_ws;
  float* biasx = (float*)((char*)d_ws + WFRAG_BYTES);

  if (use_ws) {
    prep<<<dim3((WFRAG_ELEMS + BIAS_ELEMS + 255) / 256), dim3(256), 0, stream>>>(
        w_in, btab, rpidx, wfrag, biasx);
    fused_mhaw<true><<<dim3(2048), dim3(256), LDS_TOTAL, stream>>>(
        x, reidx, w_in, b_in, btab, rpidx, wfrag, biasx, out);
  } else {
    fused_mhaw<false><<<dim3(2048), dim3(256), LDS_TOTAL, stream>>>(
        x, reidx, w_in, b_in, btab, rpidx, nullptr, nullptr, out);
  }
}